// Round 8
// baseline (207.017 us; speedup 1.0000x reference)
//
#include <hip/hip_runtime.h>
#include <hip/hip_fp16.h>

// Problem constants (fixed by setup_inputs)
#define B_   8
#define H_   512
#define W_   1024
#define FH_  128
#define FW_  256
#define TW   64
#define TH   16
#define HW_  (TW + 2)    // 66
#define HH_  (TH + 2)    // 18
#define NHALO (HH_ * HW_) // 1188
#define FR_  8           // staged flow rows
#define FC_  20          // staged flow cols
#define NSLOT 256

__device__ __forceinline__ float wave_reduce(float v) {
    #pragma unroll
    for (int off = 32; off > 0; off >>= 1) v += __shfl_down(v, off, 64);
    return v;
}

// Horizontal 3-col sums of the 5 SSIM quantities from one packed LDS row.
__device__ __forceinline__ void hrow(const __half2* __restrict__ s,
                                     float& hA, float& hB, float& hAA, float& hBB, float& hAB) {
    const float2 p0 = __half22float2(s[0]);
    const float2 p1 = __half22float2(s[1]);
    const float2 p2 = __half22float2(s[2]);
    hA  = p0.x + p1.x + p2.x;
    hB  = p0.y + p1.y + p2.y;
    hAA = fmaf(p0.x, p0.x, fmaf(p1.x, p1.x, p2.x * p2.x));
    hBB = fmaf(p0.y, p0.y, fmaf(p1.y, p1.y, p2.y * p2.y));
    hAB = fmaf(p0.x, p0.y, fmaf(p1.x, p1.y, p2.x * p2.y));
}

// All in-flight state for one halo pixel: 15 issued loads + lerp weights.
struct Taps {
    float a0, a1, a2;                    // img1 r,g,b
    float r00, r01, r10, r11;            // img2 ch0 taps
    float g00, g01, g10, g11;            // img2 ch1 taps
    float b00, b01, b10, b11;            // img2 ch2 taps
    float swx, swy;
    int   ly, lxh;
    bool  inb;
};

__global__ __launch_bounds__(256, 4)
void fused_main(const float* __restrict__ flow, const float* __restrict__ img1,
                const float* __restrict__ img2, const float* __restrict__ mask,
                float* __restrict__ accum) {
    // XCD-aware swizzle: 4096 blocks = 8 XCDs x 512; each XCD owns one batch image.
    const int bid = blockIdx.x;
    const int lin = (bid & 7) * 512 + (bid >> 3);
    const int b   = lin >> 9;            // 0..7
    const int rem = lin & 511;
    const int ty0 = (rem >> 4) * TH;     // 32 y-tiles
    const int tx0 = (rem & 15) * TW;     // 16 x-tiles
    const int tid = threadIdx.x;

    __shared__ __half2 sP[3][HH_][HW_];          // packed (img1, warp) tiles
    __shared__ float   sF[2][FR_][FC_];          // flow footprint

    const uint32_t plane = (uint32_t)H_ * W_;
    const float* f0  = flow + (size_t)b * 2 * FH_ * FW_;
    const float* f1  = f0 + FH_ * FW_;
    const float* i10 = img1 + (size_t)b * 3 * plane;
    const float* i11 = i10 + plane;
    const float* i12 = i11 + plane;
    const float* i20 = img2 + (size_t)b * 3 * plane;
    const float* i21 = i20 + plane;
    const float* i22 = i21 + plane;

    // ---- Phase 0: stage flow footprint (clamped) ----
    const int fx0s = (tx0 > 0) ? (int)((float)(tx0 - 1) * (255.0f / 1023.0f)) : 0;
    const int fy0s = (ty0 > 0) ? (int)((float)(ty0 - 1) * (127.0f / 511.0f)) : 0;
    for (int i = tid; i < 2 * FR_ * FC_; i += 256) {
        const int ch = i / (FR_ * FC_);
        const int r  = (i - ch * FR_ * FC_) / FC_;
        const int cc = i - ch * FR_ * FC_ - r * FC_;
        const int sy = min(fy0s + r, FH_ - 1);
        const int sx = min(fx0s + cc, FW_ - 1);
        const float* fp = ch ? f1 : f0;
        sF[ch][r][cc] = fp[(uint32_t)sy * FW_ + (uint32_t)sx];
    }

    // ---- Mask loads (independent; overlap with staging latency) ----
    const int lx  = tid & 63;            // column 0..63
    const int lyg = tid >> 6;            // row group 0..3
    const int rb  = lyg * 4;
    const float* mb = mask + (size_t)b * plane;
    const uint32_t mb0 = (uint32_t)(ty0 + rb) * W_ + (uint32_t)(tx0 + lx);
    float mreg[4];
    #pragma unroll
    for (int k = 0; k < 4; ++k) mreg[k] = mb[mb0 + (uint32_t)k * W_];

    __syncthreads();

    // ---- Phase 1: stage halo, 2-slot batched issue for MLP ----
    auto issue_slot = [&](int s) -> Taps {
        Taps t;
        const int iraw = tid + s * 256;
        const int i  = min(iraw, NHALO - 1);
        const int ly = i / HW_;
        const int lxh = i - ly * HW_;
        const int gy = ty0 + ly - 1;
        const int gx = tx0 + lxh - 1;
        t.ly = ly; t.lxh = lxh;
        t.inb = (gy >= 0 && gy < H_ && gx >= 0 && gx < W_);
        const int gyc = min(max(gy, 0), H_ - 1);
        const int gxc = min(max(gx, 0), W_ - 1);
        const uint32_t p = (uint32_t)gyc * W_ + (uint32_t)gxc;

        // flow upsample from LDS footprint (bilinear align_corners)
        const float yc = gyc * (127.0f / 511.0f);
        const float xc = gxc * (255.0f / 1023.0f);
        const int y0 = (int)yc, x0 = (int)xc;
        const float wy = yc - (float)y0, wx = xc - (float)x0;
        const int yr = y0 - fy0s, xr = x0 - fx0s;
        const float a00 = sF[0][yr][xr],     a01 = sF[0][yr][xr + 1];
        const float a10 = sF[0][yr + 1][xr], a11 = sF[0][yr + 1][xr + 1];
        const float c00 = sF[1][yr][xr],     c01 = sF[1][yr][xr + 1];
        const float c10 = sF[1][yr + 1][xr], c11 = sF[1][yr + 1][xr + 1];
        const float fxt = fmaf(wx, a01 - a00, a00);
        const float fxb = fmaf(wx, a11 - a10, a10);
        const float fx  = fmaf(wy, fxb - fxt, fxt);
        const float fyt = fmaf(wx, c01 - c00, c00);
        const float fyb = fmaf(wx, c11 - c10, c10);
        const float fy  = fmaf(wy, fyb - fyt, fyt);

        // grid_sample border, align_corners: sample at (gx+4fx, gy+4fy)
        const float gxs = fminf(fmaxf(fmaf(4.0f, fx, (float)gxc), 0.0f), (float)(W_ - 1));
        const float gys = fminf(fmaxf(fmaf(4.0f, fy, (float)gyc), 0.0f), (float)(H_ - 1));
        const int sx0 = (int)gxs, sy0 = (int)gys;
        const int dx = (sx0 < W_ - 1) ? 1 : 0;
        const int dyw = (sy0 < H_ - 1) ? W_ : 0;
        t.swx = gxs - (float)sx0;
        t.swy = gys - (float)sy0;
        const uint32_t p00 = (uint32_t)sy0 * W_ + (uint32_t)sx0;
        const uint32_t p01 = p00 + dx;
        const uint32_t p10 = p00 + dyw;
        const uint32_t p11 = p00 + dyw + dx;

        // 15 independent loads — all issued before any consumption
        t.a0  = i10[p];   t.a1  = i11[p];   t.a2  = i12[p];
        t.r00 = i20[p00]; t.r01 = i20[p01]; t.r10 = i20[p10]; t.r11 = i20[p11];
        t.g00 = i21[p00]; t.g01 = i21[p01]; t.g10 = i21[p10]; t.g11 = i21[p11];
        t.b00 = i22[p00]; t.b01 = i22[p01]; t.b10 = i22[p10]; t.b11 = i22[p11];
        return t;
    };

    auto commit_slot = [&](const Taps& t, int s) {
        const float rt = fmaf(t.swx, t.r01 - t.r00, t.r00);
        const float rbt = fmaf(t.swx, t.r11 - t.r10, t.r10);
        const float v20 = fmaf(t.swy, rbt - rt, rt);
        const float gt = fmaf(t.swx, t.g01 - t.g00, t.g00);
        const float gbt = fmaf(t.swx, t.g11 - t.g10, t.g10);
        const float v21 = fmaf(t.swy, gbt - gt, gt);
        const float bt = fmaf(t.swx, t.b01 - t.b00, t.b00);
        const float bbt = fmaf(t.swx, t.b11 - t.b10, t.b10);
        const float v22 = fmaf(t.swy, bbt - bt, bt);
        const float z = t.inb ? 1.0f : 0.0f;
        const bool wr = (s < 4) || (tid + s * 256 < NHALO);
        if (wr) {
            sP[0][t.ly][t.lxh] = __floats2half2_rn(t.a0 * z, v20 * z);
            sP[1][t.ly][t.lxh] = __floats2half2_rn(t.a1 * z, v21 * z);
            sP[2][t.ly][t.lxh] = __floats2half2_rn(t.a2 * z, v22 * z);
        }
    };

    {
        Taps t0 = issue_slot(0);
        Taps t1 = issue_slot(1);
        commit_slot(t0, 0); commit_slot(t1, 1);
        Taps t2 = issue_slot(2);
        Taps t3 = issue_slot(3);
        commit_slot(t2, 2); commit_slot(t3, 3);
        Taps t4 = issue_slot(4);
        commit_slot(t4, 4);
    }

    __syncthreads();

    // ---- Rolling 3x3 SSIM: 1 column x 4 consecutive rows per thread ----
    const float inv9 = 1.0f / 9.0f;
    const float C1 = 0.0001f, C2 = 0.0009f;
    float dist[4] = {0.f, 0.f, 0.f, 0.f};
    float l1s [4] = {0.f, 0.f, 0.f, 0.f};

    #pragma unroll
    for (int c = 0; c < 3; ++c) {
        float hA0,hB0,hAA0,hBB0,hAB0;
        float hA1,hB1,hAA1,hBB1,hAB1;
        float hA2,hB2,hAA2,hBB2,hAB2;
        hrow(&sP[c][rb + 0][lx], hA0,hB0,hAA0,hBB0,hAB0);
        hrow(&sP[c][rb + 1][lx], hA1,hB1,hAA1,hBB1,hAB1);
        #pragma unroll
        for (int k = 0; k < 4; ++k) {
            hrow(&sP[c][rb + k + 2][lx], hA2,hB2,hAA2,hBB2,hAB2);
            const float sA  = hA0  + hA1  + hA2;
            const float sB  = hB0  + hB1  + hB2;
            const float sAA = hAA0 + hAA1 + hAA2;
            const float sBB = hBB0 + hBB1 + hBB2;
            const float sAB = hAB0 + hAB1 + hAB2;
            const float mx  = sA * inv9, my = sB * inv9;
            const float vx  = fmaf(-mx, mx, sAA * inv9);
            const float vy  = fmaf(-my, my, sBB * inv9);
            const float vxy = fmaf(-mx, my, sAB * inv9);
            const float numt = (2.f * mx * my + C1) * (2.f * vxy + C2);
            const float dent = fmaf(fmaf(mx, mx, fmaf(my, my, C1)), (vx + vy + C2), 1e-12f);
            const float ssim = numt * __builtin_amdgcn_rcpf(dent);
            dist[k] += fminf(fmaxf((1.0f - ssim) * 0.5f, 0.f), 1.f);
            const float2 ctr = __half22float2(sP[c][rb + k + 1][lx + 1]);
            l1s[k] += fabsf(ctr.x - ctr.y);
            hA0 = hA1; hB0 = hB1; hAA0 = hAA1; hBB0 = hBB1; hAB0 = hAB1;
            hA1 = hA2; hB1 = hB2; hAA1 = hAA2; hBB1 = hBB2; hAB1 = hAB2;
        }
    }

    float num_acc = 0.f, den_acc = 0.f;
    #pragma unroll
    for (int k = 0; k < 4; ++k) {
        const float pmv = 0.28333334f * dist[k] + 0.05f * l1s[k];  // 0.85/3, 0.15/3
        const float m   = (mreg[k] > 0.5f) ? 1.f : 0.f;
        num_acc = fmaf(pmv, m, num_acc);
        den_acc += m;
    }

    float num = wave_reduce(num_acc);
    float den = wave_reduce(den_acc);
    __shared__ float rn[4], rd[4];
    const int wid = tid >> 6, lane = tid & 63;
    if (lane == 0) { rn[wid] = num; rd[wid] = den; }
    __syncthreads();
    if (tid == 0) {
        float* slot = accum + (size_t)(bid & (NSLOT - 1)) * 4;
        atomicAdd(&slot[0], rn[0] + rn[1] + rn[2] + rn[3]);
        atomicAdd(&slot[1], rd[0] + rd[1] + rd[2] + rd[3]);
    }
}

// Smoothness loss on raw flow: sum |dx| and |dy| separately (different counts).
__global__ __launch_bounds__(256)
void smooth_kernel(const float* __restrict__ flow, float* __restrict__ accum) {
    const int N = B_ * 2 * FH_ * FW_;
    float dxs = 0.f, dys = 0.f;
    for (int i = blockIdx.x * 256 + threadIdx.x; i < N; i += gridDim.x * 256) {
        const float f = flow[i];
        const int x = i & (FW_ - 1);
        const int y = (i >> 8) & (FH_ - 1);
        if (x < FW_ - 1) dxs += fabsf(f - flow[i + 1]);
        if (y < FH_ - 1) dys += fabsf(f - flow[i + FW_]);
    }
    dxs = wave_reduce(dxs);
    dys = wave_reduce(dys);
    __shared__ float rn[4], rd[4];
    const int wid = threadIdx.x >> 6, lane = threadIdx.x & 63;
    if (lane == 0) { rn[wid] = dxs; rd[wid] = dys; }
    __syncthreads();
    if (threadIdx.x == 0) {
        float* slot = accum + (size_t)blockIdx.x * 4;
        atomicAdd(&slot[2], rn[0] + rn[1] + rn[2] + rn[3]);
        atomicAdd(&slot[3], rd[0] + rd[1] + rd[2] + rd[3]);
    }
}

// Reduce the 256 accumulator slots and emit the 3 outputs.
__global__ __launch_bounds__(256)
void finalize_kernel(const float* __restrict__ accum, float* __restrict__ out) {
    const int t = threadIdx.x;
    float num = accum[t * 4 + 0];
    float den = accum[t * 4 + 1];
    float dxs = accum[t * 4 + 2];
    float dys = accum[t * 4 + 3];
    num = wave_reduce(num); den = wave_reduce(den);
    dxs = wave_reduce(dxs); dys = wave_reduce(dys);
    __shared__ float r[4][4];
    const int wid = t >> 6, lane = t & 63;
    if (lane == 0) { r[wid][0] = num; r[wid][1] = den; r[wid][2] = dxs; r[wid][3] = dys; }
    __syncthreads();
    if (t == 0) {
        const float tn = r[0][0] + r[1][0] + r[2][0] + r[3][0];
        const float td = r[0][1] + r[1][1] + r[2][1] + r[3][1];
        const float tx = r[0][2] + r[1][2] + r[2][2] + r[3][2];
        const float ty = r[0][3] + r[1][3] + r[2][3] + r[3][3];
        const float photo   = tn / fmaxf(td, 1.0f);
        const float mean_dx = tx / (float)(B_ * 2 * FH_ * (FW_ - 1));
        const float mean_dy = ty / (float)(B_ * 2 * (FH_ - 1) * FW_);
        const float smooth  = mean_dx + mean_dy;
        out[0] = photo + 0.1f * smooth;   // total
        out[1] = photo;
        out[2] = smooth;
    }
}

extern "C" void kernel_launch(void* const* d_in, const int* in_sizes, int n_in,
                              void* d_out, int out_size, void* d_ws, size_t ws_size,
                              hipStream_t stream) {
    const float* flow = (const float*)d_in[0];
    const float* img1 = (const float*)d_in[1];
    const float* img2 = (const float*)d_in[2];
    const float* mask = (const float*)d_in[3];
    float* out   = (float*)d_out;
    float* accum = (float*)d_ws;   // NSLOT x [num, den, dx_sum, dy_sum]

    hipMemsetAsync(accum, 0, NSLOT * 4 * sizeof(float), stream);
    smooth_kernel<<<NSLOT, 256, 0, stream>>>(flow, accum);
    fused_main<<<(W_ / TW) * (H_ / TH) * B_, 256, 0, stream>>>(flow, img1, img2, mask, accum);
    finalize_kernel<<<1, 256, 0, stream>>>(accum, out);
}

// Round 11
// 187.896 us; speedup vs baseline: 1.1018x; 1.1018x over previous
//
#include <hip/hip_runtime.h>
#include <hip/hip_fp16.h>

// Problem constants (fixed by setup_inputs)
#define B_   8
#define H_   512
#define W_   1024
#define FH_  128
#define FW_  256
#define TW   64
#define TH   16
#define HW_  (TW + 2)    // 66
#define HH_  (TH + 2)    // 18
#define NHALO (HH_ * HW_) // 1188
#define FR_  8           // staged flow rows
#define FC_  20          // staged flow cols
#define NSLOT 256
#define PLANE (H_ * W_)  // 524288

struct alignas(8) H4 { __half2 a; __half2 b; };   // (r,g) (b,pad)

__device__ __forceinline__ float wave_reduce(float v) {
    #pragma unroll
    for (int off = 32; off > 0; off >>= 1) v += __shfl_down(v, off, 64);
    return v;
}

// Horizontal 3-col sums of the 5 SSIM quantities from one packed LDS row.
__device__ __forceinline__ void hrow(const __half2* __restrict__ s,
                                     float& hA, float& hB, float& hAA, float& hBB, float& hAB) {
    const float2 p0 = __half22float2(s[0]);
    const float2 p1 = __half22float2(s[1]);
    const float2 p2 = __half22float2(s[2]);
    hA  = p0.x + p1.x + p2.x;
    hB  = p0.y + p1.y + p2.y;
    hAA = fmaf(p0.x, p0.x, fmaf(p1.x, p1.x, p2.x * p2.x));
    hBB = fmaf(p0.y, p0.y, fmaf(p1.y, p1.y, p2.y * p2.y));
    hAB = fmaf(p0.x, p0.y, fmaf(p1.x, p1.y, p2.x * p2.y));
}

// Prepass: repack img2 planes (float, CHW) -> interleaved half4 per pixel.
__global__ __launch_bounds__(256)
void pack_img2(const float* __restrict__ img2, H4* __restrict__ pk) {
    const int total = B_ * PLANE;
    const int stride = gridDim.x * 256 * 4;
    for (int base = (blockIdx.x * 256 + threadIdx.x) * 4; base < total; base += stride) {
        const int b = base >> 19;                 // /PLANE
        const int p = base & (PLANE - 1);
        const float* pr = img2 + (size_t)b * 3 * PLANE;
        const float4 r  = *(const float4*)&pr[p];
        const float4 g  = *(const float4*)&pr[p + PLANE];
        const float4 bl = *(const float4*)&pr[p + 2 * PLANE];
        H4* o = pk + (size_t)b * PLANE + p;
        o[0] = { __floats2half2_rn(r.x, g.x), __floats2half2_rn(bl.x, 0.f) };
        o[1] = { __floats2half2_rn(r.y, g.y), __floats2half2_rn(bl.y, 0.f) };
        o[2] = { __floats2half2_rn(r.z, g.z), __floats2half2_rn(bl.z, 0.f) };
        o[3] = { __floats2half2_rn(r.w, g.w), __floats2half2_rn(bl.w, 0.f) };
    }
}

// Fused: per 64x16 tile, stage flow footprint in LDS, then (66x18) halo of
// packed (img1, warped img2) half2 in LDS, rolling-window 3x3 SSIM, masked
// accumulation into 256 spread slots. PK=1: gather from interleaved half4.
template <int PK>
__global__ __launch_bounds__(256, 8)
void fused_main(const float* __restrict__ flow, const float* __restrict__ img1,
                const float* __restrict__ img2, const float* __restrict__ mask,
                const H4* __restrict__ pk, float* __restrict__ accum) {
    // XCD-aware swizzle: 4096 blocks = 8 XCDs x 512; each XCD owns one batch image.
    const int bid = blockIdx.x;
    const int lin = (bid & 7) * 512 + (bid >> 3);
    const int b   = lin >> 9;            // 0..7
    const int rem = lin & 511;
    const int ty0 = (rem >> 4) * TH;     // 32 y-tiles
    const int tx0 = (rem & 15) * TW;     // 16 x-tiles
    const int tid = threadIdx.x;

    __shared__ __half2 sP[3][HH_][HW_];          // packed (img1, warp) tiles
    __shared__ float   sF[2][FR_][FC_];          // flow footprint

    const float* f0  = flow + (size_t)b * 2 * FH_ * FW_;
    const float* f1  = f0 + FH_ * FW_;
    const float* i10 = img1 + (size_t)b * 3 * PLANE;
    const float* i11 = i10 + PLANE;
    const float* i12 = i11 + PLANE;
    const float* i20 = img2 + (size_t)b * 3 * PLANE;
    const float* i21 = i20 + PLANE;
    const float* i22 = i21 + PLANE;
    const H4*    pkb = pk + (size_t)b * PLANE;

    // ---- Phase 0: stage flow footprint (clamped) ----
    const int fx0s = (tx0 > 0) ? (int)((float)(tx0 - 1) * (255.0f / 1023.0f)) : 0;
    const int fy0s = (ty0 > 0) ? (int)((float)(ty0 - 1) * (127.0f / 511.0f)) : 0;
    for (int i = tid; i < 2 * FR_ * FC_; i += 256) {
        const int ch = i / (FR_ * FC_);
        const int r  = (i - ch * FR_ * FC_) / FC_;
        const int cc = i - ch * FR_ * FC_ - r * FC_;
        const int sy = min(fy0s + r, FH_ - 1);
        const int sx = min(fx0s + cc, FW_ - 1);
        const float* fp = ch ? f1 : f0;
        sF[ch][r][cc] = fp[(uint32_t)sy * FW_ + (uint32_t)sx];
    }

    // ---- Mask loads (independent; overlap with staging latency) ----
    const int lx  = tid & 63;            // column 0..63
    const int lyg = tid >> 6;            // row group 0..3
    const int rb  = lyg * 4;
    const float* mb = mask + (size_t)b * PLANE;
    const uint32_t mb0 = (uint32_t)(ty0 + rb) * W_ + (uint32_t)(tx0 + lx);
    float mreg[4];
    #pragma unroll
    for (int k = 0; k < 4; ++k) mreg[k] = mb[mb0 + (uint32_t)k * W_];

    __syncthreads();

    // ---- Phase 1: stage halo (img1 + warped img2) ----
    for (int i = tid; i < NHALO; i += 256) {
        const int ly = i / HW_;
        const int lxh = i - ly * HW_;
        const int gy = ty0 + ly - 1;
        const int gx = tx0 + lxh - 1;
        float v10 = 0.f, v11 = 0.f, v12 = 0.f;
        float v20 = 0.f, v21 = 0.f, v22 = 0.f;
        if (gy >= 0 && gy < H_ && gx >= 0 && gx < W_) {
            const uint32_t p = (uint32_t)gy * W_ + (uint32_t)gx;
            v10 = i10[p]; v11 = i11[p]; v12 = i12[p];

            // flow upsample from LDS footprint (bilinear align_corners)
            const float yc = gy * (127.0f / 511.0f);
            const float xc = gx * (255.0f / 1023.0f);
            const int y0 = (int)yc, x0 = (int)xc;
            const float wy = yc - (float)y0, wx = xc - (float)x0;
            const int yr = y0 - fy0s, xr = x0 - fx0s;
            const float a00 = sF[0][yr][xr],     a01 = sF[0][yr][xr + 1];
            const float a10 = sF[0][yr + 1][xr], a11 = sF[0][yr + 1][xr + 1];
            const float c00 = sF[1][yr][xr],     c01 = sF[1][yr][xr + 1];
            const float c10 = sF[1][yr + 1][xr], c11 = sF[1][yr + 1][xr + 1];
            const float fxt = fmaf(wx, a01 - a00, a00);
            const float fxb = fmaf(wx, a11 - a10, a10);
            const float fx  = fmaf(wy, fxb - fxt, fxt);
            const float fyt = fmaf(wx, c01 - c00, c00);
            const float fyb = fmaf(wx, c11 - c10, c10);
            const float fy  = fmaf(wy, fyb - fyt, fyt);

            // grid_sample border, align_corners: sample at (gx+4fx, gy+4fy)
            const float gxs = fminf(fmaxf(fmaf(4.0f, fx, (float)gx), 0.0f), (float)(W_ - 1));
            const float gys = fminf(fmaxf(fmaf(4.0f, fy, (float)gy), 0.0f), (float)(H_ - 1));
            const int sx0 = (int)gxs, sy0 = (int)gys;
            const int sx1 = min(sx0 + 1, W_ - 1);
            const int sy1 = min(sy0 + 1, H_ - 1);
            const float swx = gxs - (float)sx0, swy = gys - (float)sy0;
            const uint32_t p00 = (uint32_t)sy0 * W_ + (uint32_t)sx0;
            const uint32_t p01 = (uint32_t)sy0 * W_ + (uint32_t)sx1;
            const uint32_t p10 = (uint32_t)sy1 * W_ + (uint32_t)sx0;
            const uint32_t p11 = (uint32_t)sy1 * W_ + (uint32_t)sx1;

            if (PK) {
                // 4 taps x 8B interleaved loads
                const H4 q00 = pkb[p00], q01 = pkb[p01], q10 = pkb[p10], q11 = pkb[p11];
                const float2 rg00 = __half22float2(q00.a), rg01 = __half22float2(q01.a);
                const float2 rg10 = __half22float2(q10.a), rg11 = __half22float2(q11.a);
                const float b00 = __low2float(q00.b), b01 = __low2float(q01.b);
                const float b10 = __low2float(q10.b), b11 = __low2float(q11.b);
                {
                    const float t = fmaf(swx, rg01.x - rg00.x, rg00.x);
                    const float u = fmaf(swx, rg11.x - rg10.x, rg10.x);
                    v20 = fmaf(swy, u - t, t);
                }
                {
                    const float t = fmaf(swx, rg01.y - rg00.y, rg00.y);
                    const float u = fmaf(swx, rg11.y - rg10.y, rg10.y);
                    v21 = fmaf(swy, u - t, t);
                }
                {
                    const float t = fmaf(swx, b01 - b00, b00);
                    const float u = fmaf(swx, b11 - b10, b10);
                    v22 = fmaf(swy, u - t, t);
                }
            } else {
                {
                    const float t = fmaf(swx, i20[p01] - i20[p00], i20[p00]);
                    const float u = fmaf(swx, i20[p11] - i20[p10], i20[p10]);
                    v20 = fmaf(swy, u - t, t);
                }
                {
                    const float t = fmaf(swx, i21[p01] - i21[p00], i21[p00]);
                    const float u = fmaf(swx, i21[p11] - i21[p10], i21[p10]);
                    v21 = fmaf(swy, u - t, t);
                }
                {
                    const float t = fmaf(swx, i22[p01] - i22[p00], i22[p00]);
                    const float u = fmaf(swx, i22[p11] - i22[p10], i22[p10]);
                    v22 = fmaf(swy, u - t, t);
                }
            }
        }
        sP[0][ly][lxh] = __floats2half2_rn(v10, v20);
        sP[1][ly][lxh] = __floats2half2_rn(v11, v21);
        sP[2][ly][lxh] = __floats2half2_rn(v12, v22);
    }

    __syncthreads();

    // ---- Rolling 3x3 SSIM: 1 column x 4 consecutive rows per thread ----
    const float inv9 = 1.0f / 9.0f;
    const float C1 = 0.0001f, C2 = 0.0009f;
    float dist[4] = {0.f, 0.f, 0.f, 0.f};
    float l1s [4] = {0.f, 0.f, 0.f, 0.f};

    #pragma unroll
    for (int c = 0; c < 3; ++c) {
        float hA0,hB0,hAA0,hBB0,hAB0;
        float hA1,hB1,hAA1,hBB1,hAB1;
        float hA2,hB2,hAA2,hBB2,hAB2;
        hrow(&sP[c][rb + 0][lx], hA0,hB0,hAA0,hBB0,hAB0);
        hrow(&sP[c][rb + 1][lx], hA1,hB1,hAA1,hBB1,hAB1);
        #pragma unroll
        for (int k = 0; k < 4; ++k) {
            hrow(&sP[c][rb + k + 2][lx], hA2,hB2,hAA2,hBB2,hAB2);
            const float sA  = hA0  + hA1  + hA2;
            const float sB  = hB0  + hB1  + hB2;
            const float sAA = hAA0 + hAA1 + hAA2;
            const float sBB = hBB0 + hBB1 + hBB2;
            const float sAB = hAB0 + hAB1 + hAB2;
            const float mx  = sA * inv9, my = sB * inv9;
            const float vx  = fmaf(-mx, mx, sAA * inv9);
            const float vy  = fmaf(-my, my, sBB * inv9);
            const float vxy = fmaf(-mx, my, sAB * inv9);
            const float numt = (2.f * mx * my + C1) * (2.f * vxy + C2);
            const float dent = fmaf(fmaf(mx, mx, fmaf(my, my, C1)), (vx + vy + C2), 1e-12f);
            const float ssim = numt * __builtin_amdgcn_rcpf(dent);
            dist[k] += fminf(fmaxf((1.0f - ssim) * 0.5f, 0.f), 1.f);
            const float2 ctr = __half22float2(sP[c][rb + k + 1][lx + 1]);
            l1s[k] += fabsf(ctr.x - ctr.y);
            hA0 = hA1; hB0 = hB1; hAA0 = hAA1; hBB0 = hBB1; hAB0 = hAB1;
            hA1 = hA2; hB1 = hB2; hAA1 = hAA2; hBB1 = hBB2; hAB1 = hAB2;
        }
    }

    float num_acc = 0.f, den_acc = 0.f;
    #pragma unroll
    for (int k = 0; k < 4; ++k) {
        const float pmv = 0.28333334f * dist[k] + 0.05f * l1s[k];  // 0.85/3, 0.15/3
        const float m   = (mreg[k] > 0.5f) ? 1.f : 0.f;
        num_acc = fmaf(pmv, m, num_acc);
        den_acc += m;
    }

    float num = wave_reduce(num_acc);
    float den = wave_reduce(den_acc);
    __shared__ float rn[4], rd[4];
    const int wid = tid >> 6, lane = tid & 63;
    if (lane == 0) { rn[wid] = num; rd[wid] = den; }
    __syncthreads();
    if (tid == 0) {
        float* slot = accum + (size_t)(bid & (NSLOT - 1)) * 4;
        atomicAdd(&slot[0], rn[0] + rn[1] + rn[2] + rn[3]);
        atomicAdd(&slot[1], rd[0] + rd[1] + rd[2] + rd[3]);
    }
}

// Smoothness loss on raw flow: sum |dx| and |dy| separately (different counts).
__global__ __launch_bounds__(256)
void smooth_kernel(const float* __restrict__ flow, float* __restrict__ accum) {
    const int N = B_ * 2 * FH_ * FW_;
    float dxs = 0.f, dys = 0.f;
    for (int i = blockIdx.x * 256 + threadIdx.x; i < N; i += gridDim.x * 256) {
        const float f = flow[i];
        const int x = i & (FW_ - 1);
        const int y = (i >> 8) & (FH_ - 1);
        if (x < FW_ - 1) dxs += fabsf(f - flow[i + 1]);
        if (y < FH_ - 1) dys += fabsf(f - flow[i + FW_]);
    }
    dxs = wave_reduce(dxs);
    dys = wave_reduce(dys);
    __shared__ float rn[4], rd[4];
    const int wid = threadIdx.x >> 6, lane = threadIdx.x & 63;
    if (lane == 0) { rn[wid] = dxs; rd[wid] = dys; }
    __syncthreads();
    if (threadIdx.x == 0) {
        float* slot = accum + (size_t)blockIdx.x * 4;
        atomicAdd(&slot[2], rn[0] + rn[1] + rn[2] + rn[3]);
        atomicAdd(&slot[3], rd[0] + rd[1] + rd[2] + rd[3]);
    }
}

// Reduce the 256 accumulator slots and emit the 3 outputs.
__global__ __launch_bounds__(256)
void finalize_kernel(const float* __restrict__ accum, float* __restrict__ out) {
    const int t = threadIdx.x;
    float num = accum[t * 4 + 0];
    float den = accum[t * 4 + 1];
    float dxs = accum[t * 4 + 2];
    float dys = accum[t * 4 + 3];
    num = wave_reduce(num); den = wave_reduce(den);
    dxs = wave_reduce(dxs); dys = wave_reduce(dys);
    __shared__ float r[4][4];
    const int wid = t >> 6, lane = t & 63;
    if (lane == 0) { r[wid][0] = num; r[wid][1] = den; r[wid][2] = dxs; r[wid][3] = dys; }
    __syncthreads();
    if (t == 0) {
        const float tn = r[0][0] + r[1][0] + r[2][0] + r[3][0];
        const float td = r[0][1] + r[1][1] + r[2][1] + r[3][1];
        const float tx = r[0][2] + r[1][2] + r[2][2] + r[3][2];
        const float ty = r[0][3] + r[1][3] + r[2][3] + r[3][3];
        const float photo   = tn / fmaxf(td, 1.0f);
        const float mean_dx = tx / (float)(B_ * 2 * FH_ * (FW_ - 1));
        const float mean_dy = ty / (float)(B_ * 2 * (FH_ - 1) * FW_);
        const float smooth  = mean_dx + mean_dy;
        out[0] = photo + 0.1f * smooth;   // total
        out[1] = photo;
        out[2] = smooth;
    }
}

extern "C" void kernel_launch(void* const* d_in, const int* in_sizes, int n_in,
                              void* d_out, int out_size, void* d_ws, size_t ws_size,
                              hipStream_t stream) {
    const float* flow = (const float*)d_in[0];
    const float* img1 = (const float*)d_in[1];
    const float* img2 = (const float*)d_in[2];
    const float* mask = (const float*)d_in[3];
    float* out   = (float*)d_out;
    float* accum = (float*)d_ws;                      // NSLOT x [num, den, dx, dy]
    H4*    pk    = (H4*)((char*)d_ws + 4096);         // packed img2 (half4/px)

    const size_t need = 4096 + sizeof(H4) * (size_t)B_ * PLANE;  // ~33.6 MB
    const bool packed = ws_size >= need;

    hipMemsetAsync(accum, 0, NSLOT * 4 * sizeof(float), stream);
    smooth_kernel<<<NSLOT, 256, 0, stream>>>(flow, accum);
    const int grid = (W_ / TW) * (H_ / TH) * B_;
    if (packed) {
        pack_img2<<<2048, 256, 0, stream>>>(img2, pk);
        fused_main<1><<<grid, 256, 0, stream>>>(flow, img1, img2, mask, pk, accum);
    } else {
        fused_main<0><<<grid, 256, 0, stream>>>(flow, img1, img2, mask, pk, accum);
    }
    finalize_kernel<<<1, 256, 0, stream>>>(accum, out);
}